// Round 6
// baseline (444.297 us; speedup 1.0000x reference)
//
#include <hip/hip_runtime.h>
#include <type_traits>

#define B_CONST 4096
#define S_CONST 4096
// T == 2 hardcoded throughout.

#define LOG2E 1.44269504088896340736f
#define LN2   0.69314718055994530942f

// Linear-space segment: actual matrix = [[p00,p01],[p10,p11]] * 2^s.
// sc rides along as the (nat-domain) gold-path score partial.
struct Lin { float p00, p01, p10, p11, sc; int s; };

__device__ __forceinline__ void lin_renorm(Lin& P) {
    float m = fmaxf(fmaxf(P.p00, P.p01), fmaxf(P.p10, P.p11));
    int ex;
    (void)frexpf(m, &ex);               // v_frexp_exp_i32_f32 — exact
    P.p00 = ldexpf(P.p00, -ex);
    P.p01 = ldexpf(P.p01, -ex);
    P.p10 = ldexpf(P.p10, -ex);
    P.p11 = ldexpf(P.p11, -ex);
    P.s += ex;
}

__device__ __forceinline__ Lin lin_compose(const Lin& A, const Lin& B) {
    Lin o;
    o.p00 = A.p00 * B.p00 + A.p01 * B.p10;
    o.p01 = A.p00 * B.p01 + A.p01 * B.p11;
    o.p10 = A.p10 * B.p00 + A.p11 * B.p10;
    o.p11 = A.p10 * B.p01 + A.p11 * B.p11;
    o.s   = A.s + B.s;
    o.sc  = A.sc + B.sc;
    lin_renorm(o);
    return o;
}

// One 256-thread block (4 waves) per row; 16 steps/lane, contiguous.
// All math in the linear semiring (plain 2x2 matmul) with exact power-of-2
// rescaling; one log2 per block at the end.
__global__ __launch_bounds__(256) void crf_row_kernel(
    const float* __restrict__ em,     // (B,S,2)
    const float* __restrict__ st,     // (2,)
    const float* __restrict__ en,     // (2,)
    const float* __restrict__ tr,     // (2,2)
    const int*   __restrict__ tags,   // (B,S)
    const int*   __restrict__ mask,   // (B,S) prefix-of-ones rows
    float* __restrict__ out)          // scalar accumulator (pre-zeroed)
{
    const int b    = blockIdx.x;
    const int tid  = threadIdx.x;
    const int lane = tid & 63;
    const int wid  = tid >> 6;         // wave chunk 0..3
    const int cb   = wid << 10;        // chunk base step
    const int c0   = cb + (lane << 4); // this lane's first step

    const float* em_row = em   + (size_t)b * S_CONST * 2;
    const int*   tg_row = tags + (size_t)b * S_CONST;
    const int*   mk     = mask + (size_t)b * S_CONST;

    // Per-wave 2-phase ballot search for L = count of leading 1s (L >= 2048).
    int v1 = mk[lane << 6];
    unsigned long long bal1 = __ballot(v1 != 0);
    int base = (__popcll(bal1) - 1) << 6;
    int v2 = mk[base + lane];
    const int L = base + __popcll(__ballot(v2 != 0));

    // nat-domain transitions (score path) + linear-domain (normalizer path)
    const float t00 = tr[0], t01 = tr[1], t10 = tr[2], t11 = tr[3];
    const float l00 = exp2f(t00 * LOG2E), l01 = exp2f(t01 * LOG2E);
    const float l10 = exp2f(t10 * LOG2E), l11 = exp2f(t11 * LOG2E);

    Lin P; P.p00 = 1.0f; P.p01 = 0.0f; P.p10 = 0.0f; P.p11 = 1.0f;
    P.s = 0; P.sc = 0.0f;

    if (c0 < L) {
        // ---- all loads up front, unguarded (addresses always in-bounds)
        const int4* tv = (const int4*)(tg_row + c0);
        int4 tq0 = tv[0], tq1 = tv[1], tq2 = tv[2], tq3 = tv[3];
        const float4* ev = (const float4*)(em_row + 2 * c0);
        float4 e0 = ev[0], e1 = ev[1], e2 = ev[2], e3 = ev[3];
        float4 e4 = ev[4], e5 = ev[5], e6 = ev[6], e7 = ev[7];

        int prev = __shfl_up(tq3.w, 1);
        if (lane == 0) prev = (cb > 0) ? tg_row[cb - 1] : 0;

        // Lane owning step 0: use U=I for the first step so its product is
        // D_0 * Q_1 * ...  (final vector is then just exp(st)); score for
        // step 0 is gated off by fg0 (it's added separately at the end).
        const bool isz = (c0 == 0);
        const float u00 = isz ? 1.0f : l00, u01 = isz ? 0.0f : l01;
        const float u10 = isz ? 0.0f : l10, u11 = isz ? 1.0f : l11;
        const float fg0 = isz ? 0.0f : 1.0f;

        float sc = 0.0f;

        auto body = [&](auto FC) {
            constexpr bool F = decltype(FC)::value;  // true: no per-step guard
            #define DSTEP(G_, E0_, E1_, TG_, U00_, U01_, U10_, U11_, FG_)          \
                do {                                                               \
                    if (F || (c0 + (G_) < L)) {                                    \
                        float d0 = exp2f((E0_) * LOG2E);                           \
                        float d1 = exp2f((E1_) * LOG2E);                           \
                        float a_ = P.p00 * (U00_) + P.p01 * (U10_);                \
                        float b_ = P.p00 * (U01_) + P.p01 * (U11_);                \
                        float c_ = P.p10 * (U00_) + P.p11 * (U10_);                \
                        float d_ = P.p10 * (U01_) + P.p11 * (U11_);                \
                        P.p00 = a_ * d0; P.p01 = b_ * d1;                          \
                        P.p10 = c_ * d0; P.p11 = d_ * d1;                          \
                        float trv = prev ? ((TG_) ? t11 : t10)                     \
                                         : ((TG_) ? t01 : t00);                    \
                        sc += (FG_) * (trv + ((TG_) ? (E1_) : (E0_)));             \
                    }                                                              \
                    prev = (TG_);                                                  \
                } while (0)

            DSTEP( 0, e0.x, e0.y, tq0.x, u00, u01, u10, u11, fg0);
            DSTEP( 1, e0.z, e0.w, tq0.y, l00, l01, l10, l11, 1.0f);
            DSTEP( 2, e1.x, e1.y, tq0.z, l00, l01, l10, l11, 1.0f);
            DSTEP( 3, e1.z, e1.w, tq0.w, l00, l01, l10, l11, 1.0f);
            DSTEP( 4, e2.x, e2.y, tq1.x, l00, l01, l10, l11, 1.0f);
            DSTEP( 5, e2.z, e2.w, tq1.y, l00, l01, l10, l11, 1.0f);
            DSTEP( 6, e3.x, e3.y, tq1.z, l00, l01, l10, l11, 1.0f);
            DSTEP( 7, e3.z, e3.w, tq1.w, l00, l01, l10, l11, 1.0f);
            lin_renorm(P);             // bounds worst-case growth: exact, cheap
            DSTEP( 8, e4.x, e4.y, tq2.x, l00, l01, l10, l11, 1.0f);
            DSTEP( 9, e4.z, e4.w, tq2.y, l00, l01, l10, l11, 1.0f);
            DSTEP(10, e5.x, e5.y, tq2.z, l00, l01, l10, l11, 1.0f);
            DSTEP(11, e5.z, e5.w, tq2.w, l00, l01, l10, l11, 1.0f);
            DSTEP(12, e6.x, e6.y, tq3.x, l00, l01, l10, l11, 1.0f);
            DSTEP(13, e6.z, e6.w, tq3.y, l00, l01, l10, l11, 1.0f);
            DSTEP(14, e7.x, e7.y, tq3.z, l00, l01, l10, l11, 1.0f);
            DSTEP(15, e7.z, e7.w, tq3.w, l00, l01, l10, l11, 1.0f);
            #undef DSTEP
        };
        // At most one lane per row (the one containing L) takes the guarded
        // instantiation; everyone else runs the branch-free one.
        if (c0 + 16 <= L) body(std::true_type{});
        else              body(std::false_type{});

        lin_renorm(P);
        P.sc = sc;
    }

    // Ordered in-wave tree (lane i holds contiguous chunk i; left * right).
    #pragma unroll
    for (int sft = 1; sft < 64; sft <<= 1) {
        Lin R;
        R.p00 = __shfl_down(P.p00, sft);
        R.p01 = __shfl_down(P.p01, sft);
        R.p10 = __shfl_down(P.p10, sft);
        R.p11 = __shfl_down(P.p11, sft);
        R.sc  = __shfl_down(P.sc,  sft);
        R.s   = __shfl_down(P.s,   sft);
        P = lin_compose(P, R);
    }

    __shared__ Lin wseg[4];
    if (lane == 0) wseg[wid] = P;      // inactive waves publish identity
    __syncthreads();

    if (tid == 0) {
        Lin T4 = wseg[0];
        #pragma unroll
        for (int w = 1; w < 4; ++w) T4 = lin_compose(T4, wseg[w]);

        float e00 = em_row[0], e01 = em_row[1];
        float st0 = st[0], st1 = st[1];
        float en0 = en[0], en1 = en[1];

        // final = exp(st) . (D_0 * Q_1 * ... * Q_{L-1}) . exp(en)
        float uu0 = exp2f(st0 * LOG2E), uu1 = exp2f(st1 * LOG2E);
        float f0 = uu0 * T4.p00 + uu1 * T4.p10;
        float f1 = uu0 * T4.p01 + uu1 * T4.p11;
        float z  = f0 * exp2f(en0 * LOG2E) + f1 * exp2f(en1 * LOG2E);
        float norm = (log2f(z) + (float)T4.s) * LN2;

        int tg0 = tg_row[0];
        int tgL = tg_row[L - 1];
        float score = (tg0 ? st1 : st0) + (tg0 ? e01 : e00) + T4.sc
                    + (tgL ? en1 : en0);

        atomicAdd(out, (norm - score) * (1.0f / (float)B_CONST));
    }
}

extern "C" void kernel_launch(void* const* d_in, const int* in_sizes, int n_in,
                              void* d_out, int out_size, void* d_ws, size_t ws_size,
                              hipStream_t stream) {
    const float* em   = (const float*)d_in[0];
    const float* st   = (const float*)d_in[1];
    const float* en   = (const float*)d_in[2];
    const float* tr   = (const float*)d_in[3];
    const int*   tags = (const int*)d_in[4];
    const int*   mask = (const int*)d_in[5];

    float* out = (float*)d_out;

    hipMemsetAsync(out, 0, sizeof(float) * out_size, stream);
    crf_row_kernel<<<B_CONST, 256, 0, stream>>>(em, st, en, tr, tags, mask, out);
}

// Round 7
// 273.406 us; speedup vs baseline: 1.6250x; 1.6250x over previous
//
#include <hip/hip_runtime.h>

#define B_CONST 4096
#define S_CONST 4096
// T == 2 hardcoded throughout.

#define LOG2E 1.44269504088896340736f
#define LN2   0.69314718055994530942f

// Linear-space segment: actual matrix = [[p00,p01],[p10,p11]] * 2^s.
// sc rides along as the (nat-domain) gold-path score partial.
struct Lin { float p00, p01, p10, p11, sc; int s; };

__device__ __forceinline__ void lin_renorm(Lin& P) {
    float m = fmaxf(fmaxf(P.p00, P.p01), fmaxf(P.p10, P.p11));
    int ex;
    (void)frexpf(m, &ex);               // v_frexp_exp_i32_f32 — exact
    P.p00 = ldexpf(P.p00, -ex);
    P.p01 = ldexpf(P.p01, -ex);
    P.p10 = ldexpf(P.p10, -ex);
    P.p11 = ldexpf(P.p11, -ex);
    P.s += ex;
}

__device__ __forceinline__ Lin lin_compose(const Lin& A, const Lin& B) {
    Lin o;
    o.p00 = A.p00 * B.p00 + A.p01 * B.p10;
    o.p01 = A.p00 * B.p01 + A.p01 * B.p11;
    o.p10 = A.p10 * B.p00 + A.p11 * B.p10;
    o.p11 = A.p10 * B.p01 + A.p11 * B.p11;
    o.s   = A.s + B.s;
    o.sc  = A.sc + B.sc;
    lin_renorm(o);
    return o;
}

// One 256-thread block (4 waves) per row; 16 steps/lane, contiguous.
// Linear-semiring scan (plain 2x2 matmul + exact pow2 rescale); one log2 per
// block. FLAT code — no lambdas/templates (R6's lambda caused 503 MB of
// scratch-spill traffic; structure matters as much as op count).
__global__ __launch_bounds__(256) void crf_row_kernel(
    const float* __restrict__ em,     // (B,S,2)
    const float* __restrict__ st,     // (2,)
    const float* __restrict__ en,     // (2,)
    const float* __restrict__ tr,     // (2,2)
    const int*   __restrict__ tags,   // (B,S)
    const int*   __restrict__ mask,   // (B,S) prefix-of-ones rows
    float* __restrict__ out)          // scalar accumulator (pre-zeroed)
{
    const int b    = blockIdx.x;
    const int tid  = threadIdx.x;
    const int lane = tid & 63;
    const int wid  = tid >> 6;         // wave chunk 0..3
    const int cb   = wid << 10;        // chunk base step
    const int c0   = cb + (lane << 4); // this lane's first step

    const float* em_row = em   + (size_t)b * S_CONST * 2;
    const int*   tg_row = tags + (size_t)b * S_CONST;
    const int*   mk     = mask + (size_t)b * S_CONST;

    // Per-wave 2-phase ballot search for L = count of leading 1s (L >= 2048).
    int v1 = mk[lane << 6];
    unsigned long long bal1 = __ballot(v1 != 0);
    int base = (__popcll(bal1) - 1) << 6;
    int v2 = mk[base + lane];
    const int L = base + __popcll(__ballot(v2 != 0));

    // nat-domain transitions (score path) + linear-domain (normalizer path)
    const float t00 = tr[0], t01 = tr[1], t10 = tr[2], t11 = tr[3];
    const float l00 = exp2f(t00 * LOG2E), l01 = exp2f(t01 * LOG2E);
    const float l10 = exp2f(t10 * LOG2E), l11 = exp2f(t11 * LOG2E);

    Lin P; P.p00 = 1.0f; P.p01 = 0.0f; P.p10 = 0.0f; P.p11 = 1.0f;
    P.s = 0; P.sc = 0.0f;

    if (c0 < L) {
        // ---- all loads up front, unguarded (addresses always in-bounds)
        const int4* tv = (const int4*)(tg_row + c0);
        int4 tq0 = tv[0], tq1 = tv[1], tq2 = tv[2], tq3 = tv[3];
        const float4* ev = (const float4*)(em_row + 2 * c0);
        float4 e0 = ev[0], e1 = ev[1], e2 = ev[2], e3 = ev[3];
        float4 e4 = ev[4], e5 = ev[5], e6 = ev[6], e7 = ev[7];

        int prev = __shfl_up(tq3.w, 1);
        if (lane == 0) prev = (cb > 0) ? tg_row[cb - 1] : 0;

        // Lane owning step 0: U=I for its first step -> product is
        // D_0 * Q_1 * ... ; final left vector is then exp(st). Step-0 score
        // is gated by fg0 and added in the epilogue instead.
        const bool isz = (c0 == 0);
        const float u00 = isz ? 1.0f : l00, u01 = isz ? 0.0f : l01;
        const float u10 = isz ? 0.0f : l10, u11 = isz ? 1.0f : l11;
        const float fg0 = isz ? 0.0f : 1.0f;

        float sc = 0.0f;
        const int myHi = min(c0 + 16, L);

        #define DSTEP_BODY(E0_, E1_, TG_, U00_, U01_, U10_, U11_, FG_)         \
            do {                                                               \
                float d0 = exp2f((E0_) * LOG2E);                               \
                float d1 = exp2f((E1_) * LOG2E);                               \
                float a_ = P.p00 * (U00_) + P.p01 * (U10_);                    \
                float b_ = P.p00 * (U01_) + P.p01 * (U11_);                    \
                float c_ = P.p10 * (U00_) + P.p11 * (U10_);                    \
                float d_ = P.p10 * (U01_) + P.p11 * (U11_);                    \
                P.p00 = a_ * d0; P.p01 = b_ * d1;                              \
                P.p10 = c_ * d0; P.p11 = d_ * d1;                              \
                float trv = prev ? ((TG_) ? t11 : t10)                         \
                                 : ((TG_) ? t01 : t00);                        \
                sc += (FG_) * (trv + ((TG_) ? (E1_) : (E0_)));                 \
                prev = (TG_);                                                  \
            } while (0)

        #define DSTEP_G(G_, E0_, E1_, TG_, U00_, U01_, U10_, U11_, FG_)        \
            do {                                                               \
                if (c0 + (G_) < myHi) {                                        \
                    DSTEP_BODY(E0_, E1_, TG_, U00_, U01_, U10_, U11_, FG_);    \
                } else {                                                       \
                    prev = (TG_);                                              \
                }                                                              \
            } while (0)

        #define ALL_STEPS(SM_)                                                 \
            SM_( 0, e0.x, e0.y, tq0.x, u00, u01, u10, u11, fg0);               \
            SM_( 1, e0.z, e0.w, tq0.y, l00, l01, l10, l11, 1.0f);              \
            SM_( 2, e1.x, e1.y, tq0.z, l00, l01, l10, l11, 1.0f);              \
            SM_( 3, e1.z, e1.w, tq0.w, l00, l01, l10, l11, 1.0f);              \
            SM_( 4, e2.x, e2.y, tq1.x, l00, l01, l10, l11, 1.0f);              \
            SM_( 5, e2.z, e2.w, tq1.y, l00, l01, l10, l11, 1.0f);              \
            SM_( 6, e3.x, e3.y, tq1.z, l00, l01, l10, l11, 1.0f);              \
            SM_( 7, e3.z, e3.w, tq1.w, l00, l01, l10, l11, 1.0f);              \
            lin_renorm(P);                                                     \
            SM_( 8, e4.x, e4.y, tq2.x, l00, l01, l10, l11, 1.0f);              \
            SM_( 9, e4.z, e4.w, tq2.y, l00, l01, l10, l11, 1.0f);              \
            SM_(10, e5.x, e5.y, tq2.z, l00, l01, l10, l11, 1.0f);              \
            SM_(11, e5.z, e5.w, tq2.w, l00, l01, l10, l11, 1.0f);              \
            SM_(12, e6.x, e6.y, tq3.x, l00, l01, l10, l11, 1.0f);              \
            SM_(13, e6.z, e6.w, tq3.y, l00, l01, l10, l11, 1.0f);              \
            SM_(14, e7.x, e7.y, tq3.z, l00, l01, l10, l11, 1.0f);              \
            SM_(15, e7.z, e7.w, tq3.w, l00, l01, l10, l11, 1.0f)

        #define DSTEP_F(G_, E0_, E1_, TG_, U00_, U01_, U10_, U11_, FG_)        \
            DSTEP_BODY(E0_, E1_, TG_, U00_, U01_, U10_, U11_, FG_)

        if (c0 + 16 <= L) {
            ALL_STEPS(DSTEP_F);        // fast path: no per-step guards
        } else {
            ALL_STEPS(DSTEP_G);        // boundary lane only (<=1 per row)
        }
        #undef DSTEP_F
        #undef ALL_STEPS
        #undef DSTEP_G
        #undef DSTEP_BODY

        lin_renorm(P);
        P.sc = sc;
    }

    // Ordered in-wave tree (lane i holds contiguous chunk i; left * right).
    #pragma unroll
    for (int sft = 1; sft < 64; sft <<= 1) {
        Lin R;
        R.p00 = __shfl_down(P.p00, sft);
        R.p01 = __shfl_down(P.p01, sft);
        R.p10 = __shfl_down(P.p10, sft);
        R.p11 = __shfl_down(P.p11, sft);
        R.sc  = __shfl_down(P.sc,  sft);
        R.s   = __shfl_down(P.s,   sft);
        P = lin_compose(P, R);
    }

    __shared__ Lin wseg[4];
    if (lane == 0) wseg[wid] = P;      // inactive waves publish identity
    __syncthreads();

    if (tid == 0) {
        Lin T4 = wseg[0];
        #pragma unroll
        for (int w = 1; w < 4; ++w) T4 = lin_compose(T4, wseg[w]);

        float e00 = em_row[0], e01 = em_row[1];
        float st0 = st[0], st1 = st[1];
        float en0 = en[0], en1 = en[1];

        // final = exp(st) . (D_0 * Q_1 * ... * Q_{L-1}) . exp(en)
        float uu0 = exp2f(st0 * LOG2E), uu1 = exp2f(st1 * LOG2E);
        float f0 = uu0 * T4.p00 + uu1 * T4.p10;
        float f1 = uu0 * T4.p01 + uu1 * T4.p11;
        float z  = f0 * exp2f(en0 * LOG2E) + f1 * exp2f(en1 * LOG2E);
        float norm = (log2f(z) + (float)T4.s) * LN2;

        int tg0 = tg_row[0];
        int tgL = tg_row[L - 1];
        float score = (tg0 ? st1 : st0) + (tg0 ? e01 : e00) + T4.sc
                    + (tgL ? en1 : en0);

        atomicAdd(out, (norm - score) * (1.0f / (float)B_CONST));
    }
}

extern "C" void kernel_launch(void* const* d_in, const int* in_sizes, int n_in,
                              void* d_out, int out_size, void* d_ws, size_t ws_size,
                              hipStream_t stream) {
    const float* em   = (const float*)d_in[0];
    const float* st   = (const float*)d_in[1];
    const float* en   = (const float*)d_in[2];
    const float* tr   = (const float*)d_in[3];
    const int*   tags = (const int*)d_in[4];
    const int*   mask = (const int*)d_in[5];

    float* out = (float*)d_out;

    hipMemsetAsync(out, 0, sizeof(float) * out_size, stream);
    crf_row_kernel<<<B_CONST, 256, 0, stream>>>(em, st, en, tr, tags, mask, out);
}

// Round 8
// 271.303 us; speedup vs baseline: 1.6376x; 1.0078x over previous
//
#include <hip/hip_runtime.h>

#define B_CONST 4096
#define S_CONST 4096
// T == 2 hardcoded throughout.

#define LOG2E 1.44269504088896340736f
#define LN2   0.69314718055994530942f

// Linear-space segment: actual matrix = [[p00,p01],[p10,p11]] * 2^s.
// sc rides along as the (nat-domain) gold-path score partial.
struct Lin { float p00, p01, p10, p11, sc; int s; };

__device__ __forceinline__ void lin_renorm(Lin& P) {
    float m = fmaxf(fmaxf(P.p00, P.p01), fmaxf(P.p10, P.p11));
    int ex;
    (void)frexpf(m, &ex);               // v_frexp_exp_i32_f32 — exact
    P.p00 = ldexpf(P.p00, -ex);
    P.p01 = ldexpf(P.p01, -ex);
    P.p10 = ldexpf(P.p10, -ex);
    P.p11 = ldexpf(P.p11, -ex);
    P.s += ex;
}

__device__ __forceinline__ Lin lin_compose(const Lin& A, const Lin& B) {
    Lin o;
    o.p00 = A.p00 * B.p00 + A.p01 * B.p10;
    o.p01 = A.p00 * B.p01 + A.p01 * B.p11;
    o.p10 = A.p10 * B.p00 + A.p11 * B.p10;
    o.p11 = A.p10 * B.p01 + A.p11 * B.p11;
    o.s   = A.s + B.s;
    o.sc  = A.sc + B.sc;
    lin_renorm(o);
    return o;
}

// Kernel 0: L = 2048 + sum(mask[2048:4096]) — mask rows are prefix-of-ones
// with L >= S/2, so the upper-half popcount IS the search. Pure coalesced
// reduction: one wave per row, 8 int4 loads/lane, no gathers.
__global__ __launch_bounds__(256) void crf_lens_kernel(
    const int* __restrict__ mask, int* __restrict__ lens)
{
    const int lane = threadIdx.x & 63;
    const int wid  = threadIdx.x >> 6;
    const int b    = blockIdx.x * 4 + wid;
    const int4* mk = (const int4*)(mask + (size_t)b * S_CONST + (S_CONST / 2));
    // upper half = 2048 ints = 512 int4; 8 per lane, coalesced.
    int s = 0;
    #pragma unroll
    for (int k = 0; k < 8; ++k) {
        int4 v = mk[lane + (k << 6)];
        s += v.x + v.y + v.z + v.w;
    }
    #pragma unroll
    for (int d = 32; d >= 1; d >>= 1) s += __shfl_down(s, d);
    if (lane == 0) lens[b] = (S_CONST / 2) + s;
}

// Kernel 1: one 256-thread block (4 waves) per row; 16 steps/lane, contiguous.
// Linear-semiring scan (2x2 matmul + exact pow2 rescale); one log2 per row.
// No mask access, no atomics, prev-tag via direct load (same line as the
// wave's own tag loads) so compute can start as soon as each lane's own
// loads land. FLAT macro code (no lambdas — R6 spill lesson).
__global__ __launch_bounds__(256) void crf_row_kernel(
    const float* __restrict__ em,     // (B,S,2)
    const float* __restrict__ st,     // (2,)
    const float* __restrict__ en,     // (2,)
    const float* __restrict__ tr,     // (2,2)
    const int*   __restrict__ tags,   // (B,S)
    const int*   __restrict__ lens,   // (B,)
    float* __restrict__ row_nll)      // (B,)
{
    const int b    = blockIdx.x;
    const int tid  = threadIdx.x;
    const int lane = tid & 63;
    const int wid  = tid >> 6;         // wave chunk 0..3
    const int c0   = (wid << 10) + (lane << 4); // this lane's first step

    const float* em_row = em   + (size_t)b * S_CONST * 2;
    const int*   tg_row = tags + (size_t)b * S_CONST;

    const int L = lens[b];             // uniform scalar load, L1-hot

    // nat-domain transitions (score path) + linear-domain (normalizer path)
    const float t00 = tr[0], t01 = tr[1], t10 = tr[2], t11 = tr[3];
    const float l00 = exp2f(t00 * LOG2E), l01 = exp2f(t01 * LOG2E);
    const float l10 = exp2f(t10 * LOG2E), l11 = exp2f(t11 * LOG2E);

    Lin P; P.p00 = 1.0f; P.p01 = 0.0f; P.p10 = 0.0f; P.p11 = 1.0f;
    P.s = 0; P.sc = 0.0f;

    if (c0 < L) {
        // ---- all loads up front, unguarded (addresses always in-bounds).
        // prev-tag load first (no dependents block on it being last).
        int prev = tg_row[(c0 > 0) ? (c0 - 1) : 0];   // value unused when c0==0
        const int4* tv = (const int4*)(tg_row + c0);
        int4 tq0 = tv[0], tq1 = tv[1], tq2 = tv[2], tq3 = tv[3];
        const float4* ev = (const float4*)(em_row + 2 * c0);
        float4 e0 = ev[0], e1 = ev[1], e2 = ev[2], e3 = ev[3];
        float4 e4 = ev[4], e5 = ev[5], e6 = ev[6], e7 = ev[7];

        // Lane owning step 0: U=I for its first step -> product is
        // D_0 * Q_1 * ... ; final left vector is then exp(st). Step-0 score
        // is gated by fg0 and added in the epilogue instead.
        const bool isz = (c0 == 0);
        const float u00 = isz ? 1.0f : l00, u01 = isz ? 0.0f : l01;
        const float u10 = isz ? 0.0f : l10, u11 = isz ? 1.0f : l11;
        const float fg0 = isz ? 0.0f : 1.0f;

        float sc = 0.0f;
        const int myHi = min(c0 + 16, L);

        #define DSTEP_BODY(E0_, E1_, TG_, U00_, U01_, U10_, U11_, FG_)         \
            do {                                                               \
                float d0 = exp2f((E0_) * LOG2E);                               \
                float d1 = exp2f((E1_) * LOG2E);                               \
                float a_ = P.p00 * (U00_) + P.p01 * (U10_);                    \
                float b_ = P.p00 * (U01_) + P.p01 * (U11_);                    \
                float c_ = P.p10 * (U00_) + P.p11 * (U10_);                    \
                float d_ = P.p10 * (U01_) + P.p11 * (U11_);                    \
                P.p00 = a_ * d0; P.p01 = b_ * d1;                              \
                P.p10 = c_ * d0; P.p11 = d_ * d1;                              \
                float trv = prev ? ((TG_) ? t11 : t10)                         \
                                 : ((TG_) ? t01 : t00);                        \
                sc += (FG_) * (trv + ((TG_) ? (E1_) : (E0_)));                 \
                prev = (TG_);                                                  \
            } while (0)

        #define DSTEP_G(G_, E0_, E1_, TG_, U00_, U01_, U10_, U11_, FG_)        \
            do {                                                               \
                if (c0 + (G_) < myHi) {                                        \
                    DSTEP_BODY(E0_, E1_, TG_, U00_, U01_, U10_, U11_, FG_);    \
                } else {                                                       \
                    prev = (TG_);                                              \
                }                                                              \
            } while (0)

        #define ALL_STEPS(SM_)                                                 \
            SM_( 0, e0.x, e0.y, tq0.x, u00, u01, u10, u11, fg0);               \
            SM_( 1, e0.z, e0.w, tq0.y, l00, l01, l10, l11, 1.0f);              \
            SM_( 2, e1.x, e1.y, tq0.z, l00, l01, l10, l11, 1.0f);              \
            SM_( 3, e1.z, e1.w, tq0.w, l00, l01, l10, l11, 1.0f);              \
            SM_( 4, e2.x, e2.y, tq1.x, l00, l01, l10, l11, 1.0f);              \
            SM_( 5, e2.z, e2.w, tq1.y, l00, l01, l10, l11, 1.0f);              \
            SM_( 6, e3.x, e3.y, tq1.z, l00, l01, l10, l11, 1.0f);              \
            SM_( 7, e3.z, e3.w, tq1.w, l00, l01, l10, l11, 1.0f);              \
            lin_renorm(P);                                                     \
            SM_( 8, e4.x, e4.y, tq2.x, l00, l01, l10, l11, 1.0f);              \
            SM_( 9, e4.z, e4.w, tq2.y, l00, l01, l10, l11, 1.0f);              \
            SM_(10, e5.x, e5.y, tq2.z, l00, l01, l10, l11, 1.0f);              \
            SM_(11, e5.z, e5.w, tq2.w, l00, l01, l10, l11, 1.0f);              \
            SM_(12, e6.x, e6.y, tq3.x, l00, l01, l10, l11, 1.0f);              \
            SM_(13, e6.z, e6.w, tq3.y, l00, l01, l10, l11, 1.0f);              \
            SM_(14, e7.x, e7.y, tq3.z, l00, l01, l10, l11, 1.0f);              \
            SM_(15, e7.z, e7.w, tq3.w, l00, l01, l10, l11, 1.0f)

        #define DSTEP_F(G_, E0_, E1_, TG_, U00_, U01_, U10_, U11_, FG_)        \
            DSTEP_BODY(E0_, E1_, TG_, U00_, U01_, U10_, U11_, FG_)

        if (c0 + 16 <= L) {
            ALL_STEPS(DSTEP_F);        // fast path: no per-step guards
        } else {
            ALL_STEPS(DSTEP_G);        // boundary lane only (<=1 per row)
        }
        #undef DSTEP_F
        #undef ALL_STEPS
        #undef DSTEP_G
        #undef DSTEP_BODY

        lin_renorm(P);
        P.sc = sc;
    }

    // Ordered in-wave tree (lane i holds contiguous chunk i; left * right).
    #pragma unroll
    for (int sft = 1; sft < 64; sft <<= 1) {
        Lin R;
        R.p00 = __shfl_down(P.p00, sft);
        R.p01 = __shfl_down(P.p01, sft);
        R.p10 = __shfl_down(P.p10, sft);
        R.p11 = __shfl_down(P.p11, sft);
        R.sc  = __shfl_down(P.sc,  sft);
        R.s   = __shfl_down(P.s,   sft);
        P = lin_compose(P, R);
    }

    __shared__ Lin wseg[4];
    if (lane == 0) wseg[wid] = P;      // inactive waves publish identity
    __syncthreads();

    if (tid == 0) {
        Lin T4 = wseg[0];
        #pragma unroll
        for (int w = 1; w < 4; ++w) T4 = lin_compose(T4, wseg[w]);

        float e00 = em_row[0], e01 = em_row[1];
        float st0 = st[0], st1 = st[1];
        float en0 = en[0], en1 = en[1];

        // final = exp(st) . (D_0 * Q_1 * ... * Q_{L-1}) . exp(en)
        float uu0 = exp2f(st0 * LOG2E), uu1 = exp2f(st1 * LOG2E);
        float f0 = uu0 * T4.p00 + uu1 * T4.p10;
        float f1 = uu0 * T4.p01 + uu1 * T4.p11;
        float z  = f0 * exp2f(en0 * LOG2E) + f1 * exp2f(en1 * LOG2E);
        float norm = (log2f(z) + (float)T4.s) * LN2;

        int tg0 = tg_row[0];
        int tgL = tg_row[L - 1];
        float score = (tg0 ? st1 : st0) + (tg0 ? e01 : e00) + T4.sc
                    + (tgL ? en1 : en0);

        row_nll[b] = norm - score;
    }
}

// Kernel 2: mean over B row NLLs -> scalar (plain store, no atomics).
__global__ __launch_bounds__(256) void crf_mean_kernel(
    const float* __restrict__ row_nll, float* __restrict__ out)
{
    const float4* rv = (const float4*)row_nll;
    float s = 0.0f;
    #pragma unroll
    for (int k = 0; k < 4; ++k) {
        float4 v = rv[threadIdx.x + (k << 8)];
        s += v.x + v.y + v.z + v.w;
    }
    #pragma unroll
    for (int d = 32; d >= 1; d >>= 1) s += __shfl_down(s, d);
    __shared__ float ws[4];
    const int lane = threadIdx.x & 63, wid = threadIdx.x >> 6;
    if (lane == 0) ws[wid] = s;
    __syncthreads();
    if (threadIdx.x == 0)
        out[0] = (ws[0] + ws[1] + ws[2] + ws[3]) * (1.0f / (float)B_CONST);
}

extern "C" void kernel_launch(void* const* d_in, const int* in_sizes, int n_in,
                              void* d_out, int out_size, void* d_ws, size_t ws_size,
                              hipStream_t stream) {
    const float* em   = (const float*)d_in[0];
    const float* st   = (const float*)d_in[1];
    const float* en   = (const float*)d_in[2];
    const float* tr   = (const float*)d_in[3];
    const int*   tags = (const int*)d_in[4];
    const int*   mask = (const int*)d_in[5];

    float* row_nll = (float*)d_ws;                   // B floats
    int*   lens    = (int*)((float*)d_ws + B_CONST); // B ints
    float* out     = (float*)d_out;

    crf_lens_kernel<<<B_CONST / 4, 256, 0, stream>>>(mask, lens);
    crf_row_kernel<<<B_CONST, 256, 0, stream>>>(em, st, en, tr, tags, lens, row_nll);
    crf_mean_kernel<<<1, 256, 0, stream>>>(row_nll, out);
}